// Round 4
// baseline (92.433 us; speedup 1.0000x reference)
//
#include <hip/hip_runtime.h>

#define NUM_CLASSES 1000
#define CPAD 1024          // histogram padded to 1024 ints (4 KB) per wave
#define ROW_N 512
#define WAVES_PER_BLOCK 4
#define BLOCK 256
#define GRID 2048          // 8192 persistent waves; 8 rows per wave at B=65536

typedef int   v4i __attribute__((ext_vector_type(4)));
typedef float v4f __attribute__((ext_vector_type(4)));

// Fused per-row mode + one-hot, persistent waves, 2-stage pipeline.
// One 64-lane wave per row-chunk; wave-private histogram -> NO barriers
// (same-wave DS ops are in-order; nothing crosses waves).
//
// Tie-break (matches reference count + earliest-first-occurrence):
// winner = row[min{p : cnt[row[p]] == M}], M = max count. Any earlier
// position with cnt==M would belong to a max-count class with an earlier
// first occurrence.
//
// M via atomic returns: final count of class c equals the post-increment
// value of the LAST update to c, so M = wave_max over all (old+1).
__global__ __launch_bounds__(BLOCK) void mode_onehot_fused(
    const int* __restrict__ in, float* __restrict__ out, int B) {
  __shared__ int cnt[WAVES_PER_BLOCK][CPAD];

  const int tid  = threadIdx.x;
  const int w    = tid >> 6;
  const int lane = tid & 63;
  const int wid  = blockIdx.x * WAVES_PER_BLOCK + w;
  const int nwaves = GRID * WAVES_PER_BLOCK;
  const int rpw  = B / nwaves;        // 8 rows per wave
  const int r0   = wid * rpw;         // contiguous chunk per wave

  // zero wave-private histogram: 4 x ds_write_b128
  v4i* cz = reinterpret_cast<v4i*>(cnt[w]);
#pragma unroll
  for (int k = 0; k < 4; ++k) cz[lane + 64 * k] = (v4i)(0);

  // prologue: load first row (2 contiguous 1 KB instructions)
  const v4i* p0 = reinterpret_cast<const v4i*>(in + (size_t)r0 * ROW_N);
  v4i va = __builtin_nontemporal_load(p0 + lane);
  v4i vb = __builtin_nontemporal_load(p0 + lane + 64);

  for (int i = 0; i < rpw; ++i) {
    // issue next row's loads FIRST -> latency hides under this row's work
    v4i nva = va, nvb = vb;
    if (i + 1 < rpw) {
      const v4i* pn = reinterpret_cast<const v4i*>(in + (size_t)(r0 + i + 1) * ROW_N);
      nva = __builtin_nontemporal_load(pn + lane);
      nvb = __builtin_nontemporal_load(pn + lane + 64);
    }

    // histogram build + running max of post-increment counts
    int m = 0;
    m = max(m, atomicAdd(&cnt[w][va.x], 1) + 1);
    m = max(m, atomicAdd(&cnt[w][va.y], 1) + 1);
    m = max(m, atomicAdd(&cnt[w][va.z], 1) + 1);
    m = max(m, atomicAdd(&cnt[w][va.w], 1) + 1);
    m = max(m, atomicAdd(&cnt[w][vb.x], 1) + 1);
    m = max(m, atomicAdd(&cnt[w][vb.y], 1) + 1);
    m = max(m, atomicAdd(&cnt[w][vb.z], 1) + 1);
    m = max(m, atomicAdd(&cnt[w][vb.w], 1) + 1);
#pragma unroll
    for (int off = 32; off >= 1; off >>= 1) m = max(m, __shfl_xor(m, off, 64));

    // Phase C: earliest position whose class has final count == M
    const int e[8] = {va.x, va.y, va.z, va.w, vb.x, vb.y, vb.z, vb.w};
    int best = 0x7FFFFFFF;
#pragma unroll
    for (int j = 0; j < 8; ++j) {
      const int pos = (j < 4) ? (4 * lane + j) : (256 + 4 * lane + (j - 4));
      if (cnt[w][e[j]] == m) best = min(best, (pos << 10) | e[j]);
    }
#pragma unroll
    for (int off = 32; off >= 1; off >>= 1) best = min(best, __shfl_xor(best, off, 64));
    const int mode = best & 1023;

    // re-zero histogram for next iteration (after Phase C reads; in-order DS)
#pragma unroll
    for (int k = 0; k < 4; ++k) cz[lane + 64 * k] = (v4i)(0);

    // one-hot write for this row: 250 nt float4 stores
    v4f* orow = reinterpret_cast<v4f*>(out + (size_t)(r0 + i) * NUM_CLASSES);
#pragma unroll
    for (int ii = lane; ii < NUM_CLASSES / 4; ii += 64) {
      v4f z;
      z.x = (4 * ii + 0 == mode) ? 1.0f : 0.0f;
      z.y = (4 * ii + 1 == mode) ? 1.0f : 0.0f;
      z.z = (4 * ii + 2 == mode) ? 1.0f : 0.0f;
      z.w = (4 * ii + 3 == mode) ? 1.0f : 0.0f;
      __builtin_nontemporal_store(z, orow + ii);
    }

    va = nva; vb = nvb;
  }
}

extern "C" void kernel_launch(void* const* d_in, const int* in_sizes, int n_in,
                              void* d_out, int out_size, void* d_ws, size_t ws_size,
                              hipStream_t stream) {
  const int* in = (const int*)d_in[0];
  float* out = (float*)d_out;
  const int B = in_sizes[0] / ROW_N;  // 65536
  mode_onehot_fused<<<GRID, BLOCK, 0, stream>>>(in, out, B);
}

// Round 6
// 62.919 us; speedup vs baseline: 1.4691x; 1.4691x over previous
//
#include <hip/hip_runtime.h>

#define NUM_CLASSES 1000
#define CPAD 1024          // histogram padded to 1024 ints (4 KB) per wave
#define ROW_N 512
#define WAVES_PER_BLOCK 4
#define BLOCK 256
#define GRID 2048          // 8192 waves, all co-resident (8 blocks/CU)
#define RPW 8              // rows per wave (65536 / 8192)

typedef int   v4i __attribute__((ext_vector_type(4)));
typedef float v4f __attribute__((ext_vector_type(4)));

// Pin BOTH compiler and DS-pipe ordering: drain all LDS ops, and forbid the
// scheduler from moving anything across. Round-5 post-timing divergence
// (absmax exactly 1.0 = "no position had cnt==M" => mode=1023 => empty row)
// is the signature of the b128 re-zero racing the next row's ds_add/ds_read
// in the DS pipe; these fences + atomic-only histogram restore remove every
// ordering assumption.
#define LDS_FENCE()                                     \
  do {                                                  \
    asm volatile("s_waitcnt lgkmcnt(0)" ::: "memory");  \
    __builtin_amdgcn_sched_barrier(0);                  \
  } while (0)

// Fused per-row mode + one-hot with BULK PHASE SEPARATION:
//   phase 1 = pure read stream (compute all 8 modes, keep in registers)
//   phase 2 = pure write stream (8 one-hot rows, 32 KB contiguous per wave)
//
// Tie-break (matches reference count + earliest-first-occurrence):
// winner = row[min{p : cnt[row[p]] == M}], M = max count. Any earlier
// position with cnt==M would belong to a max-count class with an earlier
// first occurrence.
//
// M via atomic returns: final count of class c equals the post-increment
// value of the LAST update to c, so M = wave_max over all (old+1).
__global__ __launch_bounds__(BLOCK) void mode_onehot_2phase(
    const int* __restrict__ in, float* __restrict__ out, int B) {
  __shared__ int cnt[WAVES_PER_BLOCK][CPAD];

  const int tid  = threadIdx.x;
  const int w    = tid >> 6;
  const int lane = tid & 63;
  const int wid  = blockIdx.x * WAVES_PER_BLOCK + w;
  const int r0   = wid * RPW;         // contiguous 8-row chunk per wave

  // one-time zero of the wave-private histogram (4 x ds_write_b128),
  // fenced before any atomics touch it
  v4i* cz = reinterpret_cast<v4i*>(cnt[w]);
#pragma unroll
  for (int k = 0; k < 4; ++k) cz[lane + 64 * k] = (v4i)(0);
  LDS_FENCE();

  int modes[RPW];  // unrolled static indexing -> stays in VGPRs

  // ---------------- Phase 1: pure-read mode computation ----------------
  const v4i* p0 = reinterpret_cast<const v4i*>(in + (size_t)r0 * ROW_N);
  v4i va = __builtin_nontemporal_load(p0 + lane);
  v4i vb = __builtin_nontemporal_load(p0 + lane + 64);

#pragma unroll
  for (int i = 0; i < RPW; ++i) {
    // issue next row's loads first -> HBM latency hides under this row's work
    v4i nva = va, nvb = vb;
    if (i + 1 < RPW) {
      const v4i* pn = reinterpret_cast<const v4i*>(in + (size_t)(r0 + i + 1) * ROW_N);
      nva = __builtin_nontemporal_load(pn + lane);
      nvb = __builtin_nontemporal_load(pn + lane + 64);
    }

    // histogram build + running max of post-increment counts
    int m = 0;
    m = max(m, atomicAdd(&cnt[w][va.x], 1) + 1);
    m = max(m, atomicAdd(&cnt[w][va.y], 1) + 1);
    m = max(m, atomicAdd(&cnt[w][va.z], 1) + 1);
    m = max(m, atomicAdd(&cnt[w][va.w], 1) + 1);
    m = max(m, atomicAdd(&cnt[w][vb.x], 1) + 1);
    m = max(m, atomicAdd(&cnt[w][vb.y], 1) + 1);
    m = max(m, atomicAdd(&cnt[w][vb.z], 1) + 1);
    m = max(m, atomicAdd(&cnt[w][vb.w], 1) + 1);
#pragma unroll
    for (int off = 32; off >= 1; off >>= 1) m = max(m, __shfl_xor(m, off, 64));

    LDS_FENCE();  // all adds retired before plain count reads

    // earliest position whose class has final count == M
    const int e[8] = {va.x, va.y, va.z, va.w, vb.x, vb.y, vb.z, vb.w};
    int best = 0x7FFFFFFF;
#pragma unroll
    for (int j = 0; j < 8; ++j) {
      const int pos = (j < 4) ? (4 * lane + j) : (256 + 4 * lane + (j - 4));
      if (cnt[w][e[j]] == m) best = min(best, (pos << 10) | e[j]);
    }
#pragma unroll
    for (int off = 32; off >= 1; off >>= 1) best = min(best, __shfl_xor(best, off, 64));
    modes[i] = best & 1023;

    LDS_FENCE();  // phase-C reads retired before the restore subs

    // restore exact zeros by subtracting the same multiset (atomic-only
    // traffic: no wide-write-vs-atomic ordering window, no TBAA ambiguity)
    atomicSub(&cnt[w][va.x], 1);
    atomicSub(&cnt[w][va.y], 1);
    atomicSub(&cnt[w][va.z], 1);
    atomicSub(&cnt[w][va.w], 1);
    atomicSub(&cnt[w][vb.x], 1);
    atomicSub(&cnt[w][vb.y], 1);
    atomicSub(&cnt[w][vb.z], 1);
    atomicSub(&cnt[w][vb.w], 1);

    LDS_FENCE();  // subs retired before next row's adds

    va = nva; vb = nvb;
  }

  // ---------------- Phase 2: pure-write one-hot stream ----------------
  // 8 rows x 250 float4 = 32 KB contiguous per wave; plain stores
  // (the harness's fill kernel proves this path runs at ~7 TB/s).
#pragma unroll
  for (int i = 0; i < RPW; ++i) {
    const int mode = modes[i];
    v4f* orow = reinterpret_cast<v4f*>(out + (size_t)(r0 + i) * NUM_CLASSES);
#pragma unroll
    for (int k = 0; k < 4; ++k) {
      const int ii = lane + 64 * k;
      if (ii < NUM_CLASSES / 4) {
        v4f z;
        z.x = (4 * ii + 0 == mode) ? 1.0f : 0.0f;
        z.y = (4 * ii + 1 == mode) ? 1.0f : 0.0f;
        z.z = (4 * ii + 2 == mode) ? 1.0f : 0.0f;
        z.w = (4 * ii + 3 == mode) ? 1.0f : 0.0f;
        orow[ii] = z;
      }
    }
  }
}

extern "C" void kernel_launch(void* const* d_in, const int* in_sizes, int n_in,
                              void* d_out, int out_size, void* d_ws, size_t ws_size,
                              hipStream_t stream) {
  const int* in = (const int*)d_in[0];
  float* out = (float*)d_out;
  const int B = in_sizes[0] / ROW_N;  // 65536
  mode_onehot_2phase<<<GRID, BLOCK, 0, stream>>>(in, out, B);
}